// Round 8
// baseline (197.603 us; speedup 1.0000x reference)
//
#include <hip/hip_runtime.h>

// Volume rendering (NeRF-style fancy_integration), f32 in/out.
// B=4, R=32768, S=64 -> 131072 rays, 64 samples.
//
// Mapping: chunk = 4 rays; each 16-lane DPP row owns one ray; each lane owns
// 4 consecutive samples -> all global traffic is float4, fully lane-linear.
// Cross-lane = 4-step DPP row scans.
//
// R8: PERSISTENT WAVES. 1024 blocks x 4 waves = 4096 waves; each wave owns
// TPW=8 chunks strided by the wave count, fully unrolled with a 2-deep
// register double-buffer: issue chunk t+1's 5 nt loads, then compute/store
// chunk t (wait = vmcnt(5), never a full drain; no rotation movs).
// Evidence: R1-R7 pinned at ~55-70us with every pipe idle; the 6.7TB/s
// harness fill runs at 9% occupancy -> the winners are continuous-issue
// grid-stride streamers, not short-lived burst waves. nt loads kept
// (R5/R7 < 59us vs 70-71us without).

#define EPS_W 1e-10f
#define DELTA_INF_V 1e10f

#define DPP_ROW_SHL(n) (0x100 | (n))
#define DPP_ROW_SHR(n) (0x110 | (n))

#define TPW 8   // chunks per wave

using f4 = __attribute__((ext_vector_type(4))) float;

template <int CTRL>
__device__ __forceinline__ float dpp_mov(float x, float old) {
    return __builtin_bit_cast(float,
        __builtin_amdgcn_update_dpp(
            __builtin_bit_cast(int, old), __builtin_bit_cast(int, x),
            CTRL, 0xf, 0xf, false));
}

// Inclusive multiply-scan within each 16-lane row (identity 1.0).
__device__ __forceinline__ float row_scan_mul(float p) {
    p *= dpp_mov<DPP_ROW_SHR(1)>(p, 1.0f);
    p *= dpp_mov<DPP_ROW_SHR(2)>(p, 1.0f);
    p *= dpp_mov<DPP_ROW_SHR(4)>(p, 1.0f);
    p *= dpp_mov<DPP_ROW_SHR(8)>(p, 1.0f);
    return p;
}

// Row sum; lane 15 of each row ends with the full row total.
__device__ __forceinline__ float row_sum(float x) {
    x += dpp_mov<DPP_ROW_SHR(1)>(x, 0.0f);
    x += dpp_mov<DPP_ROW_SHR(2)>(x, 0.0f);
    x += dpp_mov<DPP_ROW_SHR(4)>(x, 0.0f);
    x += dpp_mov<DPP_ROW_SHR(8)>(x, 0.0f);
    return x;
}

__global__ __launch_bounds__(256) void volrend_kernel(
    const float* __restrict__ rgb,      // [n_rays, 64, 3]
    const float* __restrict__ sigma,    // [n_rays, 64]
    const float* __restrict__ z_vals,   // [n_rays, 64]
    float* __restrict__ rgb_out,        // [n_rays, 3]
    float* __restrict__ depth_out,      // [n_rays]
    float* __restrict__ weights_out,    // [n_rays, 64]
    int n_rays)
{
    const int lane = threadIdx.x & 63;
    const int wave = threadIdx.x >> 6;
    const long long wave_g = (long long)blockIdx.x * (blockDim.x >> 6) + wave;
    const long long W = (long long)gridDim.x * (blockDim.x >> 6);  // total waves

    const int j   = lane & 15;   // lane within row: samples 4j..4j+3
    const int row = lane >> 4;   // ray within chunk
    const long long n_chunks = n_rays >> 2;

    // double-buffered registers (unrolled loop -> distinct regs, no movs)
    f4 sgb[2], zzb[2], c0b[2], c1b[2], c2b[2];

    auto load_chunk = [&](long long ch, int b) {
        sgb[b] = __builtin_nontemporal_load(
            reinterpret_cast<const f4*>(sigma + ch * 256) + lane);
        zzb[b] = __builtin_nontemporal_load(
            reinterpret_cast<const f4*>(z_vals + ch * 256) + lane);
        const f4* rgb4 = reinterpret_cast<const f4*>(rgb + ch * 768 + (long long)lane * 12);
        c0b[b] = __builtin_nontemporal_load(rgb4 + 0);   // r0 g0 b0 r1
        c1b[b] = __builtin_nontemporal_load(rgb4 + 1);   // g1 b1 r2 g2
        c2b[b] = __builtin_nontemporal_load(rgb4 + 2);   // b2 r3 g3 b3
    };

    auto process_chunk = [&](long long ch, int b) {
        const f4 sg = sgb[b], zz = zzb[b];
        const f4 c0 = c0b[b], c1 = c1b[b], c2 = c2b[b];

        // ---- deltas ----
        const float zn = dpp_mov<DPP_ROW_SHL(1)>(zz.x, 0.0f); // next lane z0
        const float d0 = zz.y - zz.x;
        const float d1 = zz.z - zz.y;
        const float d2 = zz.w - zz.z;
        const float d3 = (j == 15) ? DELTA_INF_V : (zn - zz.w);

        // ---- alpha = 1 - exp(-delta * relu(sigma)) ----
        const float a0 = 1.0f - __expf(-d0 * fmaxf(sg.x, 0.0f));
        const float a1 = 1.0f - __expf(-d1 * fmaxf(sg.y, 0.0f));
        const float a2 = 1.0f - __expf(-d2 * fmaxf(sg.z, 0.0f));
        const float a3 = 1.0f - __expf(-d3 * fmaxf(sg.w, 0.0f));

        // ---- exclusive cumprod of (1 - a + eps) ----
        const float q0 = 1.0f - a0 + EPS_W;
        const float q1 = 1.0f - a1 + EPS_W;
        const float q2 = 1.0f - a2 + EPS_W;
        const float q3 = 1.0f - a3 + EPS_W;
        const float P0 = q0;
        const float P1 = P0 * q1;
        const float P2 = P1 * q2;
        const float P3 = P2 * q3;

        const float R = row_scan_mul(P3);
        const float E = dpp_mov<DPP_ROW_SHR(1)>(R, 1.0f);  // lane0 = 1

        const float w0 = a0 * E;
        const float w1 = a1 * (E * P0);
        const float w2 = a2 * (E * P1);
        const float w3 = a3 * (E * P2);

        // ---- weights: one contiguous nt float4 store per lane ----
        f4 wv; wv.x = w0; wv.y = w1; wv.z = w2; wv.w = w3;
        __builtin_nontemporal_store(
            wv, reinterpret_cast<f4*>(weights_out + ch * 256) + lane);

        // ---- weighted sums (rgb + depth) ----
        float pr = w0 * c0.x + w1 * c0.w + w2 * c1.z + w3 * c2.y;
        float pg = w0 * c0.y + w1 * c1.x + w2 * c1.w + w3 * c2.z;
        float pb = w0 * c0.z + w1 * c1.y + w2 * c2.x + w3 * c2.w;
        float pd = w0 * zz.x + w1 * zz.y + w2 * zz.z + w3 * zz.w;

        pr = row_sum(pr);
        pg = row_sum(pg);
        pb = row_sum(pb);
        pd = row_sum(pd);

        if (j == 15) {
            const long long ray = ch * 4 + row;
            __builtin_nontemporal_store(pr, rgb_out + ray * 3 + 0);
            __builtin_nontemporal_store(pg, rgb_out + ray * 3 + 1);
            __builtin_nontemporal_store(pb, rgb_out + ray * 3 + 2);
            __builtin_nontemporal_store(pd, depth_out + ray);
        }
    };

    // ---- software-pipelined persistent loop over TPW strided chunks ----
    if (wave_g >= n_chunks) return;
    load_chunk(wave_g, 0);

    #pragma unroll
    for (int t = 0; t < TPW; ++t) {
        const long long cur = wave_g + (long long)t * W;
        if (cur >= n_chunks) break;
        const long long nxt = cur + W;
        if ((t + 1 < TPW) && (nxt < n_chunks)) load_chunk(nxt, (t + 1) & 1);
        process_chunk(cur, t & 1);
    }
}

extern "C" void kernel_launch(void* const* d_in, const int* in_sizes, int n_in,
                              void* d_out, int out_size, void* d_ws, size_t ws_size,
                              hipStream_t stream) {
    const float* rgb    = (const float*)d_in[0];   // [B,R,S,3]
    const float* sigma  = (const float*)d_in[1];   // [B,R,S,1]
    const float* z_vals = (const float*)d_in[2];   // [B,R,S,1]

    const int n_rays = in_sizes[1] / 64;           // B*R = 131072

    float* out         = (float*)d_out;
    float* rgb_out     = out;                              // n_rays*3
    float* depth_out   = out + (long long)n_rays * 3;      // n_rays
    float* weights_out = out + (long long)n_rays * 4;      // n_rays*64

    const int block = 256;                         // 4 waves/block
    const int n_chunks = n_rays / 4;               // 32768
    const int chunks_per_block = (block / 64) * TPW;   // 32
    const int grid = (n_chunks + chunks_per_block - 1) / chunks_per_block;  // 1024

    volrend_kernel<<<grid, block, 0, stream>>>(
        rgb, sigma, z_vals, rgb_out, depth_out, weights_out, n_rays);
}